// Round 4
// baseline (160.133 us; speedup 1.0000x reference)
//
#include <hip/hip_runtime.h>

#define HH 512
#define WW 512
#define PD 544                          // 512 + 2*16
#define PADN (3 * PD * PD)              // 887808 (bf16 elements)
#define OUTN (3 * HH * WW)              // 786432
#define NB 128
#define KSTR 16384                      // 128*128 floats between taps

// ---------------- pad + out-zero kernel: fp32 img -> bf16 edge-padded ----------------
__global__ __launch_bounds__(256) void pad_kernel(const float* __restrict__ img,
                                                  unsigned short* __restrict__ gpad,
                                                  float* __restrict__ out) {
    int idx = blockIdx.x * 256 + threadIdx.x;
    if (idx < OUTN) out[idx] = 0.0f;      // zero atomic target (replaces memset dispatch)
    if (idx >= PADN) return;
    int c  = idx / (PD * PD);
    int r  = idx - c * (PD * PD);
    int py = r / PD;
    int px = r - py * PD;
    int iy = min(max(py - 16, 0), HH - 1);
    int ix = min(max(px - 16, 0), WW - 1);
    union { float f; unsigned u; } v;
    v.f = img[(c * HH + iy) * WW + ix];
    unsigned u = v.u + 0x7FFFu + ((v.u >> 16) & 1u);   // round-to-nearest-even bf16
    gpad[idx] = (unsigned short)(u >> 16);
}

// ---- async global->LDS (wave-uniform LDS base; HW scatters lane i at base+i*size) ----
__device__ __forceinline__ void async4(const float* g, float* l) {
    __builtin_amdgcn_global_load_lds((const __attribute__((address_space(1))) void*)g,
                                     (__attribute__((address_space(3))) void*)l, 4, 0, 0);
}
__device__ __forceinline__ void async16u(const unsigned short* g, unsigned short* l) {
    __builtin_amdgcn_global_load_lds((const __attribute__((address_space(1))) void*)g,
                                     (__attribute__((address_space(3))) void*)l, 16, 0, 0);
}

__device__ __forceinline__ float bflo(unsigned d) {
    union { unsigned u; float f; } x; x.u = d << 16; return x.f;
}
__device__ __forceinline__ float bfhi(unsigned d) {
    union { unsigned u; float f; } x; x.u = d & 0xFFFF0000u; return x.f;
}

// ---------------- main kernel ----------------
// Grid = 3 p-splits x 128 h x 2 wt = 768 single-wave (64-thread) blocks.
// Lane owns (wb, ALL 4 dy, 4 oj, 3 c) = 48 accumulators. One iter = one padded
// row p' (p = 4h+p'): img window read ONCE serves 1584 FMAs (4x better LDS
// amplification than round 3). Image bf16 in LDS -> 9 ds_read_b64/c at 8 B/lane
// stride (2-way, conflict-free; fixes round-3's 7.7M b128 conflicts).
// Weights fp32 lane-major ring-4; the row about to be overwritten (dy=3's u=p'-3)
// is pulled to registers before issuing the u=p'+1 stage. Single wave => no
// s_barrier; sync is s_waitcnt vmcnt(0) at iter top only. 3 p-splits combine
// via fp32 atomicAdd into the pad_kernel-zeroed output.
// LDS = 33.8 KB (s_w) + 3.5 KB (s_img) = 37.3 KB -> 4 blocks/CU.
__global__ __launch_bounds__(64) void reblur_kernel(const unsigned short* __restrict__ gpad,
                                                    const float* __restrict__ Kern,
                                                    float* __restrict__ out) {
    __shared__ float s_w[4][33][64];            // 33792 B, ring over u (mod 4)
    __shared__ unsigned short s_img[2][3][296]; // 3552 B, ring over p' (mod 2)

    const int lane = threadIdx.x;               // 0..63
    const int s    = blockIdx.x >> 8;           // p-split 0..2
    const int bb   = blockIdx.x & 255;
    const int h    = bb >> 1;                   // 0..127
    const int wt   = bb & 1;                    // 0..1
    const int p0   = 12 * s;                    // padded-row range [p0, p0+12)
    const int p1   = p0 + 12;
    const int kofs = h * NB + wt * 64 + lane;   // per-lane weight offset within a tap

    // ---- prologue: stage weight rows [max(0,p0-3)..p0] and image row p0 ----
    for (int u = max(0, p0 - 3); u <= p0; ++u)
        for (int v = 0; v < 33; ++v)
            async4(Kern + ((u * 33 + v) * KSTR + kofs), &s_w[u & 3][v][0]);
    if (lane < 36)
        for (int c = 0; c < 3; ++c)
            async16u(gpad + ((size_t)(c * PD + 4 * h + p0) * PD + 256 * wt) + 8 * lane,
                     &s_img[p0 & 1][c][0]);

    float acc[3][4][4];
#pragma unroll
    for (int c = 0; c < 3; ++c)
#pragma unroll
        for (int dy = 0; dy < 4; ++dy)
#pragma unroll
            for (int oj = 0; oj < 4; ++oj) acc[c][dy][oj] = 0.0f;

#pragma unroll 1
    for (int pp = p0; pp < p1; ++pp) {
        // all stages issued last iter have landed
        asm volatile("s_waitcnt vmcnt(0)" ::: "memory");

        // dy=3 weights (u=pp-3) -> regs: its ring slot is the one the u=pp+1
        // stage overwrites. Drain the reads before issuing that stage.
        float wreg[33];
        const int u3 = pp - 3;
        if (u3 >= 0) {
#pragma unroll
            for (int v = 0; v < 33; ++v) wreg[v] = s_w[u3 & 3][v][lane];
        }
        asm volatile("s_waitcnt lgkmcnt(0)" ::: "memory");

        // ---- issue next iter's stages (fire-and-forget, ~3400 cyc to land) ----
        if (pp + 1 < p1) {
            const int un = pp + 1;
            if (un <= 32)
                for (int v = 0; v < 33; ++v)
                    async4(Kern + ((un * 33 + v) * KSTR + kofs), &s_w[un & 3][v][0]);
            if (lane < 36)
                for (int c = 0; c < 3; ++c)
                    async16u(gpad + ((size_t)(c * PD + 4 * h + un) * PD + 256 * wt) + 8 * lane,
                             &s_img[un & 1][c][0]);
        }

        // ---- read + expand the 3 channel windows (36 bf16 each, 9 b64/c) ----
        float wf[3][36];
        const int slot = pp & 1;
#pragma unroll
        for (int c = 0; c < 3; ++c) {
#pragma unroll
            for (int j = 0; j < 9; ++j) {
                const uint2 d = *(const uint2*)&s_img[slot][c][4 * lane + 4 * j];
                wf[c][4 * j + 0] = bflo(d.x);
                wf[c][4 * j + 1] = bfhi(d.x);
                wf[c][4 * j + 2] = bflo(d.y);
                wf[c][4 * j + 3] = bfhi(d.y);
            }
        }

        // ---- dy = 0..2: weights from LDS (rows pp, pp-1, pp-2) ----
#pragma unroll
        for (int dy = 0; dy < 3; ++dy) {
            const int u = pp - dy;
            if (u >= 0 && u <= 32) {                    // uniform branch
                const float* wp = &s_w[u & 3][0][lane];
#pragma unroll
                for (int v = 0; v < 33; ++v) {
                    const float w = wp[v * 64];
#pragma unroll
                    for (int c = 0; c < 3; ++c)
#pragma unroll
                        for (int oj = 0; oj < 4; ++oj)
                            acc[c][dy][oj] = fmaf(wf[c][v + oj], w, acc[c][dy][oj]);
                }
            }
        }
        // ---- dy = 3: weights from regs ----
        if (u3 >= 0) {
#pragma unroll
            for (int v = 0; v < 33; ++v) {
#pragma unroll
                for (int c = 0; c < 3; ++c)
#pragma unroll
                    for (int oj = 0; oj < 4; ++oj)
                        acc[c][3][oj] = fmaf(wf[c][v + oj], wreg[v], acc[c][3][oj]);
            }
        }
    }

    // ---- epilogue: 3 p-splits accumulate into zeroed out ----
#pragma unroll
    for (int c = 0; c < 3; ++c)
#pragma unroll
        for (int dy = 0; dy < 4; ++dy) {
            float* op = out + (size_t)(c * HH + 4 * h + dy) * WW + 4 * (wt * 64 + lane);
#pragma unroll
            for (int oj = 0; oj < 4; ++oj) atomicAdd(op + oj, acc[c][dy][oj]);
        }
}

// ---------------- fallback (ws too small): naive but correct ----------------
__global__ __launch_bounds__(256) void reblur_naive(const float* __restrict__ img,
                                                    const float* __restrict__ Kern,
                                                    float* __restrict__ out) {
    const int lane = threadIdx.x & 63;
    const int dy   = threadIdx.x >> 6;
    const int c    = blockIdx.x >> 8;
    const int bb   = blockIdx.x & 255;
    const int h    = bb >> 1;
    const int wt   = bb & 1;
    const int wb   = wt * 64 + lane;
    const int y    = 4 * h + dy;

    float acc[4] = {0.f, 0.f, 0.f, 0.f};
    const float* kb = Kern + h * NB + wb;
#pragma unroll 1
    for (int u = 0; u < 33; ++u) {
        const int iy = min(max(y + u - 16, 0), HH - 1);
        float row[36];
#pragma unroll
        for (int e = 0; e < 36; ++e) {
            const int ix = min(max(4 * wb + e - 16, 0), WW - 1);
            row[e]       = img[(c * HH + iy) * WW + ix];
        }
#pragma unroll
        for (int v = 0; v < 33; ++v) {
            const float w = kb[(u * 33 + v) * KSTR];
#pragma unroll
            for (int oj = 0; oj < 4; ++oj)
                acc[oj] = fmaf(row[v + oj], w, acc[oj]);
        }
    }
    float4 o;
    o.x = acc[0]; o.y = acc[1]; o.z = acc[2]; o.w = acc[3];
    *reinterpret_cast<float4*>(out + (size_t)(c * HH + y) * WW + 4 * wb) = o;
}

extern "C" void kernel_launch(void* const* d_in, const int* in_sizes, int n_in,
                              void* d_out, int out_size, void* d_ws, size_t ws_size,
                              hipStream_t stream) {
    const float* img  = (const float*)d_in[0];
    const float* Kern = (const float*)d_in[1];
    float* out        = (float*)d_out;

    if (ws_size >= (size_t)PADN * sizeof(unsigned short)) {
        unsigned short* gpad = (unsigned short*)d_ws;
        pad_kernel<<<(PADN + 255) / 256, 256, 0, stream>>>(img, gpad, out);
        reblur_kernel<<<768, 64, 0, stream>>>(gpad, Kern, out);
    } else {
        reblur_naive<<<768, 256, 0, stream>>>(img, Kern, out);
    }
}